// Round 12
// baseline (348.897 us; speedup 1.0000x reference)
//
#include <hip/hip_runtime.h>
#include <hip/hip_fp16.h>
#include <math.h>

// GCN 2-layer forward. Round 12: col[] sorted by src-segment within each
// node's edge list (k_build 2048-counter counting sort) so concurrent pull
// waves sweep h in loose lock-step -> L2-resident gather windows.
//
// ws layout (byte offsets, MiB = 1<<20):
//   0        : bcnt[B]       (i32, B=ceil(N/128))
//   64KB     : dinv[N]       (f32)
//   512KB    : rowptr[N+1]   (i32)
//   1MiB     : col[E]        (i32)   ~12.2 MiB
//   14MB-128K: Wt1, Wt2      (f16 128x128 each, [n][k])
//   18MiB    : h[N*128]      (f16)   ~24.4 MiB
//   44MiB    : agg[N*128]    (f16)   ~24.4 MiB (written after build)
//   44MiB    : staging[B*5120] (i32, ~15.3MiB) OVERLAPS agg: dead before agg written

#define MB (1u << 20)
#define BCAP 5120
#define EBLK 512  // edge-processing blocks in k_append; blocks >= EBLK do wprep

typedef _Float16 f16x8 __attribute__((ext_vector_type(8)));
typedef float f32x4 __attribute__((ext_vector_type(4)));

// Blocks 0..EBLK-1: bucketed edge staging. Blocks EBLK..: fused weight prep.
__global__ __launch_bounds__(256) void k_append(const int* __restrict__ src,
                                                const int* __restrict__ dst,
                                                int* __restrict__ bcnt,
                                                int* __restrict__ staging,
                                                const float* __restrict__ W1,
                                                const float* __restrict__ W2,
                                                _Float16* __restrict__ Wt1,
                                                _Float16* __restrict__ Wt2,
                                                int E, int N, int B) {
  if (blockIdx.x >= EBLK) {  // ---- fused wprep ----
    int idx = (blockIdx.x - EBLK) * 256 + threadIdx.x;  // 0..32767
    const float* W = (idx < 16384) ? W1 : W2;
    _Float16* Wt = (idx < 16384) ? Wt1 : Wt2;
    int i = idx & 16383;
    int k = i >> 7, n = i & 127;
    Wt[n * 128 + k] = (_Float16)W[k * 128 + n];
    return;
  }
  __shared__ int lh[1024];
  __shared__ int lb[1024];
  const int t = threadIdx.x;
  const int per = (E + EBLK - 1) / EBLK;
  const int e0 = blockIdx.x * per;
  const int e1 = min(e0 + per, E);

  for (int i = t; i < B; i += 256) lh[i] = 0;
  __syncthreads();
  for (int e = e0 + t; e < e1; e += 256) {
    int d = dst[e], s = src[e];
    if ((unsigned)d < (unsigned)N && (unsigned)s < (unsigned)N)
      atomicAdd(&lh[d >> 7], 1);
  }
  __syncthreads();
  for (int i = t; i < B; i += 256) {
    int c = lh[i];
    lb[i] = c ? atomicAdd(&bcnt[i], c) : 0;
  }
  __syncthreads();
  for (int i = t; i < B; i += 256) lh[i] = 0;
  __syncthreads();
  for (int e = e0 + t; e < e1; e += 256) {
    int d = dst[e], s = src[e];
    if ((unsigned)d < (unsigned)N && (unsigned)s < (unsigned)N) {
      int b = d >> 7;
      int lp = atomicAdd(&lh[b], 1);
      int pos = lb[b] + lp;
      if (pos < BCAP)
        staging[(size_t)b * BCAP + pos] = ((d & 127) << 25) | s;
    }
  }
}

// One block per bucket. Counting sort by (local dst, src>>13) so each node's
// col entries are grouped in ascending src-segment order.
__global__ __launch_bounds__(256) void k_build(const int* __restrict__ staging,
                                               const int* __restrict__ bcnt,
                                               int* __restrict__ rowptr,
                                               float* __restrict__ dinv,
                                               int* __restrict__ col, int N, int B) {
  __shared__ int red[256];
  __shared__ int cnt2[2048];  // [node 0..127][seg 0..15] hist -> excl offsets
  __shared__ int cur2[2048];
  const int b = blockIdx.x;
  const int t = threadIdx.x;
  const int cnt = min(bcnt[b], BCAP);
  const int* stg = staging + (size_t)b * BCAP;

  // exclusive prefix over previous buckets' clamped counts (bcnt ~3KB, L2-hot)
  int partial = 0;
  for (int i = t; i < b; i += 256) partial += min(bcnt[i], BCAP);
  red[t] = partial;
  for (int i = t; i < 2048; i += 256) cnt2[i] = 0;
  __syncthreads();
  #pragma unroll
  for (int o = 128; o > 0; o >>= 1) {
    if (t < o) red[t] += red[t + o];
    __syncthreads();
  }
  const int ebase = red[0];
  __syncthreads();  // red reused by the scan below

  // histogram by (dl, seg)
  for (int i = t; i < cnt; i += 256) {
    unsigned p = (unsigned)stg[i];
    int dl = p >> 25;
    int s = p & 0x1FFFFFF;
    int seg = s >> 13;  // 0..15 for N < 131072 (2MB h-slice per segment)
    atomicAdd(&cnt2[dl * 16 + seg], 1);
  }
  __syncthreads();

  // exclusive scan over the 2048 counters (8 per thread)
  int loc[8];
  int lsum = 0;
  #pragma unroll
  for (int j = 0; j < 8; j++) { loc[j] = cnt2[t * 8 + j]; lsum += loc[j]; }
  red[t] = lsum;
  __syncthreads();
  for (int d = 1; d < 256; d <<= 1) {
    int v = (t >= d) ? red[t - d] : 0;
    __syncthreads();
    red[t] += v;
    __syncthreads();
  }
  int excl = (t == 0) ? 0 : red[t - 1];
  #pragma unroll
  for (int j = 0; j < 8; j++) { int c = loc[j]; cnt2[t * 8 + j] = excl; excl += c; }
  __syncthreads();

  for (int i = t; i < 2048; i += 256) cur2[i] = cnt2[i];
  if (t < 128) {
    int node = b * 128 + t;
    if (node < N) {
      int start = cnt2[t * 16];
      int next = (t < 127) ? cnt2[(t + 1) * 16] : cnt;
      rowptr[node] = ebase + start;
      dinv[node] = rsqrtf((float)(next - start + 1));  // + self-loop
    }
  }
  if (b == B - 1 && t == 0) rowptr[N] = ebase + cnt;
  __syncthreads();

  // scatter (segment-sorted within each node)
  for (int i = t; i < cnt; i += 256) {
    unsigned p = (unsigned)stg[i];
    int dl = p >> 25;
    int s = p & 0x1FFFFFF;
    int seg = s >> 13;
    int lp = atomicAdd(&cur2[dl * 16 + seg], 1);
    col[ebase + lp] = s;
  }
}

// --- GEMM input loaders ---
__device__ __forceinline__ void load8(const float* X, size_t base, int kg,
                                      bool relu, _Float16* tmp) {
  float4 v0 = *reinterpret_cast<const float4*>(X + base + kg * 8);
  float4 v1 = *reinterpret_cast<const float4*>(X + base + kg * 8 + 4);
  if (relu) {
    v0.x = fmaxf(v0.x, 0.f); v0.y = fmaxf(v0.y, 0.f);
    v0.z = fmaxf(v0.z, 0.f); v0.w = fmaxf(v0.w, 0.f);
    v1.x = fmaxf(v1.x, 0.f); v1.y = fmaxf(v1.y, 0.f);
    v1.z = fmaxf(v1.z, 0.f); v1.w = fmaxf(v1.w, 0.f);
  }
  tmp[0] = (_Float16)v0.x; tmp[1] = (_Float16)v0.y;
  tmp[2] = (_Float16)v0.z; tmp[3] = (_Float16)v0.w;
  tmp[4] = (_Float16)v1.x; tmp[5] = (_Float16)v1.y;
  tmp[6] = (_Float16)v1.z; tmp[7] = (_Float16)v1.w;
}
__device__ __forceinline__ void load8(const __half* X, size_t base, int kg,
                                      bool relu, _Float16* tmp) {
  uint4 u = *reinterpret_cast<const uint4*>(X + base + kg * 8);
  const _Float16* p = reinterpret_cast<const _Float16*>(&u);
  #pragma unroll
  for (int j = 0; j < 8; j++) {
    _Float16 f = p[j];
    if (relu && (float)f < 0.f) f = (_Float16)0.f;
    tmp[j] = f;
  }
}

// H[M x 128] = (f16)(act(X) @ W) * dinv[row]. 64-row tile, 4 waves, MFMA.
template <bool RELU_IN, typename InT>
__global__ __launch_bounds__(256) void k_gemm(const InT* __restrict__ X,
                                              const _Float16* __restrict__ Wt,
                                              const float* __restrict__ dinv,
                                              __half* __restrict__ H, int M) {
  __shared__ __align__(16) _Float16 Xs[64 * 128];   // 16 KB
  __shared__ __align__(16) _Float16 Ws[128 * 128];  // 32 KB, [n][k]
  const int rb = blockIdx.x * 64;
  const int t = threadIdx.x;

  for (int idx = t; idx < 1024; idx += 256) {
    int row = idx >> 4, kg = idx & 15;
    int grow = rb + row;
    _Float16 tmp[8];
    if (grow < M) {
      load8(X, (size_t)grow * 128, kg, RELU_IN, tmp);
    } else {
      #pragma unroll
      for (int j = 0; j < 8; j++) tmp[j] = (_Float16)0.f;
    }
    int g = kg ^ (row & 7);
    *reinterpret_cast<uint4*>(&Xs[row * 128 + g * 8]) = *reinterpret_cast<uint4*>(tmp);
  }
  for (int idx = t; idx < 2048; idx += 256) {
    int n = idx >> 4, kg = idx & 15;
    uint4 v = *reinterpret_cast<const uint4*>(Wt + n * 128 + kg * 8);
    int g = kg ^ (n & 7);
    *reinterpret_cast<uint4*>(&Ws[n * 128 + g * 8]) = v;
  }
  __syncthreads();

  const int wid = t >> 6;
  const int l = t & 63;
  const int lrow = wid * 16 + (l & 15);
  const int kq = l >> 4;

  f16x8 afrag[4];
  #pragma unroll
  for (int kc = 0; kc < 4; kc++) {
    int kg = kc * 4 + kq;
    int g = kg ^ (lrow & 7);
    afrag[kc] = *reinterpret_cast<const f16x8*>(&Xs[lrow * 128 + g * 8]);
  }
  float dv[4];
  #pragma unroll
  for (int i = 0; i < 4; i++) {
    int grow = rb + wid * 16 + kq * 4 + i;
    dv[i] = (grow < M) ? dinv[grow] : 0.f;
  }

  #pragma unroll 2
  for (int nt = 0; nt < 8; nt++) {
    const int n = nt * 16 + (l & 15);
    f32x4 acc = {};
    #pragma unroll
    for (int kc = 0; kc < 4; kc++) {
      int kg = kc * 4 + kq;
      int g = kg ^ (n & 7);
      f16x8 bfrag = *reinterpret_cast<const f16x8*>(&Ws[n * 128 + g * 8]);
      acc = __builtin_amdgcn_mfma_f32_16x16x32_f16(afrag[kc], bfrag, acc, 0, 0, 0);
    }
    #pragma unroll
    for (int i = 0; i < 4; i++) {
      int grow = rb + wid * 16 + kq * 4 + i;
      if (grow < M)
        H[(size_t)grow * 128 + nt * 16 + (l & 15)] = __float2half(acc[i] * dv[i]);
    }
  }
}

// out[i] = dinv[i]*(hs[i] + sum_j hs[col_j]) + b ; optional ReLU.
// One wave per node; 32 lanes per row, 4 fp16 (8B) per lane -> 2 edges/instr.
template <bool RELU_OUT, typename OutT>
__global__ __launch_bounds__(256) void k_pull(const __half* __restrict__ hs,
                                              const int* __restrict__ rowptr,
                                              const int* __restrict__ col,
                                              const float* __restrict__ dinv,
                                              const float* __restrict__ bias,
                                              OutT* __restrict__ out, int N) {
  int node = blockIdx.x * 4 + (threadIdx.x >> 6);
  if (node >= N) return;
  node = __builtin_amdgcn_readfirstlane(node);
  const int lane = threadIdx.x & 63;
  const int half = lane >> 5;
  const int fo = (lane & 31) << 2;
  const int start = __builtin_amdgcn_readfirstlane(rowptr[node]);
  const int cnt = __builtin_amdgcn_readfirstlane(rowptr[node + 1]) - start;

  float4 a0 = make_float4(0.f, 0.f, 0.f, 0.f);
  float4 a1 = a0, a2 = a0, a3 = a0;

#define GATHER(sidx, dstacc)                                                   \
  {                                                                            \
    const __half2* p_ =                                                        \
        reinterpret_cast<const __half2*>(hs + (size_t)(sidx) * 128 + fo);      \
    float2 f0_ = __half22float2(p_[0]);                                        \
    float2 f1_ = __half22float2(p_[1]);                                        \
    dstacc.x += f0_.x; dstacc.y += f0_.y;                                      \
    dstacc.z += f1_.x; dstacc.w += f1_.y;                                      \
  }

  int k = 0;
  for (; k + 8 <= cnt; k += 8) {
    int s0 = col[start + k + 0 + half];
    int s1 = col[start + k + 2 + half];
    int s2 = col[start + k + 4 + half];
    int s3 = col[start + k + 6 + half];
    GATHER(s0, a0);
    GATHER(s1, a1);
    GATHER(s2, a2);
    GATHER(s3, a3);
  }
  for (; k + 2 <= cnt; k += 2) {
    int s = col[start + k + half];
    GATHER(s, a0);
  }
  if (k < cnt) {
    int s = col[start + k];
    if (!half) {
      GATHER(s, a1);
    }
  }
#undef GATHER

  float4 acc;
  acc.x = (a0.x + a1.x) + (a2.x + a3.x);
  acc.y = (a0.y + a1.y) + (a2.y + a3.y);
  acc.z = (a0.z + a1.z) + (a2.z + a3.z);
  acc.w = (a0.w + a1.w) + (a2.w + a3.w);
  acc.x += __shfl_xor(acc.x, 32, 64);
  acc.y += __shfl_xor(acc.y, 32, 64);
  acc.z += __shfl_xor(acc.z, 32, 64);
  acc.w += __shfl_xor(acc.w, 32, 64);

  if (!half) {
    const __half2* sp = reinterpret_cast<const __half2*>(hs + (size_t)node * 128 + fo);
    float2 s0 = __half22float2(sp[0]);
    float2 s1 = __half22float2(sp[1]);
    float di = dinv[node];
    float4 bv = *reinterpret_cast<const float4*>(bias + fo);
    float4 o;
    o.x = fmaf(di, acc.x + s0.x, bv.x);
    o.y = fmaf(di, acc.y + s0.y, bv.y);
    o.z = fmaf(di, acc.z + s1.x, bv.z);
    o.w = fmaf(di, acc.w + s1.y, bv.w);
    if (RELU_OUT) {
      o.x = fmaxf(o.x, 0.f); o.y = fmaxf(o.y, 0.f);
      o.z = fmaxf(o.z, 0.f); o.w = fmaxf(o.w, 0.f);
    }
    if constexpr (sizeof(OutT) == 2) {
      __half2 p0 = __float22half2_rn(make_float2(o.x, o.y));
      __half2 p1 = __float22half2_rn(make_float2(o.z, o.w));
      __half2* op = reinterpret_cast<__half2*>((__half*)out + (size_t)node * 128 + fo);
      op[0] = p0;
      op[1] = p1;
    } else {
      *reinterpret_cast<float4*>((float*)out + (size_t)node * 128 + fo) = o;
    }
  }
}

extern "C" void kernel_launch(void* const* d_in, const int* in_sizes, int n_in,
                              void* d_out, int out_size, void* d_ws, size_t ws_size,
                              hipStream_t stream) {
  const float* x  = (const float*)d_in[0];
  const int*   ei = (const int*)d_in[1];
  const float* W1 = (const float*)d_in[2];
  const float* b1 = (const float*)d_in[3];
  const float* W2 = (const float*)d_in[4];
  const float* b2 = (const float*)d_in[5];
  float* out = (float*)d_out;

  const int N = in_sizes[0] / 128;
  const int E = in_sizes[1] / 2;
  const int B = (N + 127) >> 7;
  const int* src = ei;
  const int* dst = ei + E;

  char* ws = (char*)d_ws;
  int*      bcnt    = (int*)     (ws);
  float*    dinv    = (float*)   (ws + 64 * 1024);
  int*      rowptr  = (int*)     (ws + 512 * 1024);
  int*      col     = (int*)     (ws + 1 * MB);
  _Float16* Wt1     = (_Float16*)(ws + 14 * MB - 128 * 1024);
  _Float16* Wt2     = (_Float16*)(ws + 14 * MB - 64 * 1024);
  __half*   h       = (__half*)  (ws + 18 * MB);
  __half*   agg     = (__half*)  (ws + 44 * MB);
  int*      staging = (int*)     (ws + 44 * MB);  // overlaps agg; dead before agg written

  dim3 b256(256);

  hipMemsetAsync(bcnt, 0, (size_t)B * 4, stream);
  k_append<<<EBLK + 128, b256, 0, stream>>>(src, dst, bcnt, staging,
                                            W1, W2, Wt1, Wt2, E, N, B);
  k_build<<<B, b256, 0, stream>>>(staging, bcnt, rowptr, dinv, col, N, B);

  dim3 ggrid((N + 63) / 64);
  dim3 pgrid((N + 3) / 4);

  k_gemm<false, float><<<ggrid, b256, 0, stream>>>(x, Wt1, dinv, h, N);
  k_pull<false, __half><<<pgrid, b256, 0, stream>>>(h, rowptr, col, dinv, b1, agg, N);

  k_gemm<true, __half><<<ggrid, b256, 0, stream>>>(agg, Wt2, dinv, h, N);
  k_pull<true, float><<<pgrid, b256, 0, stream>>>(h, rowptr, col, dinv, b2, out, N);
}